// Round 4
// baseline (314.102 us; speedup 1.0000x reference)
//
#include <hip/hip_runtime.h>
#include <stdint.h>

#define B_ 1024
#define D_ 784
#define H_ 1024
#define BH_ (B_ * H_)
#define LOG2E 1.4426950408889634f

// Segments: {0,200,392,592,784}; G ranges: first 3 spans.
// nade_main v2: 1 wave = 1 full row (16 h per lane, two 8-trees + 2 rcp),
// 64-lane DPP reduce (6 stages), lane63 stores float4 directly.
// NO LDS, NO barriers, NO cross-wave epilogue (R3: occupancy not the limiter;
// VALU-issue-bound -> cut per-step overhead instead).
// Grid = 4 seg x 256 row-blocks (4 rows/block) = 1024 blocks = 4/CU resident.
// __launch_bounds__(256,4) -> 128-VGPR cap: no spill risk (R2 lesson).
// VWb: per (step i, hb) 1KB image of 512 ushorts: [0,256) V bf16, [256,512) W*log2e bf16.
// ws: VWb [788][4][512] ushort 3.23 MB | G [3][B][H] fp32 12.6 MB

__device__ __forceinline__ unsigned short bf16_rne(float x) {
    unsigned b = __float_as_uint(x);
    return (unsigned short)((b + 0x7FFFu + ((b >> 16) & 1u)) >> 16);
}

__device__ __forceinline__ int seg_bound(int s) {
    const int b[5] = {0, 200, 392, 592, 784};
    return b[s];
}

// ---------- fat prep (unchanged, verified) ----------
__global__ __launch_bounds__(256) void prep(const float* __restrict__ V,
                                            const float* __restrict__ W,
                                            const float* __restrict__ px,
                                            unsigned short* __restrict__ VWb,
                                            float* __restrict__ G) {
    __shared__ float smem[1056];
    const int t = threadIdx.x;

    if (blockIdx.x < 800) {
        int i0 = (blockIdx.x % 25) * 32;
        int h0 = (blockIdx.x / 25) * 32;
        int tx = t & 31, ty = t >> 5;   // 32 x 8
        int hb = h0 >> 8, hr = h0 & 255;
#pragma unroll
        for (int j = 0; j < 4; ++j) {
            int i = i0 + ty + j * 8;
            if (i < D_)
                VWb[((size_t)i * 4 + hb) * 512 + hr + tx] = bf16_rne(V[(size_t)i * H_ + h0 + tx]);
        }
#pragma unroll
        for (int j = 0; j < 4; ++j) {
            int h = h0 + ty + j * 8;
            int i = i0 + tx;
            float v = 0.f;
            if (i < D_) v = W[(size_t)h * D_ + i] * LOG2E;
            smem[(ty + j * 8) * 33 + tx] = v;
        }
        __syncthreads();
#pragma unroll
        for (int j = 0; j < 4; ++j) {
            int i = i0 + ty + j * 8;
            if (i < D_)
                VWb[((size_t)i * 4 + hb) * 512 + 256 + hr + tx] = bf16_rne(smem[tx * 33 + ty + j * 8]);
        }
    } else {
        float* xs = smem;          // [8][64]
        float* ws = smem + 512;    // [8][64]
        int idx = blockIdx.x - 800;
        int r   = idx >> 8;                       // 0..2
        int b0  = (idx & 15) * 64;
        int h0  = ((idx >> 4) & 15) * 64;
        int j0s = seg_bound(r), j1s = seg_bound(r + 1);

        const int tb = t >> 4, th = t & 15;       // 16x16, each 4b x 4h
        float acc[4][4];
#pragma unroll
        for (int bi = 0; bi < 4; ++bi)
#pragma unroll
            for (int hh = 0; hh < 4; ++hh) acc[bi][hh] = 0.f;

        const int xb = t >> 3;                    // 0..31
        const int xj = t & 7;                     // 0..7
        const int wh = t >> 1, wj = (t & 1) * 4;  // for t < 128

        for (int j0 = j0s; j0 < j1s; j0 += 8) {   // range lengths all %8 == 0
            float xv0 = px[(size_t)(b0 + xb) * D_ + j0 + xj];
            float xv1 = px[(size_t)(b0 + 32 + xb) * D_ + j0 + xj];
            float4 wv = make_float4(0, 0, 0, 0);
            if (t < 128) wv = *(const float4*)(W + (size_t)(h0 + wh) * D_ + j0 + wj);
            __syncthreads();
            xs[xj * 64 + xb]      = xv0;
            xs[xj * 64 + 32 + xb] = xv1;
            if (t < 128) {
                ws[(wj + 0) * 64 + wh] = wv.x * LOG2E;
                ws[(wj + 1) * 64 + wh] = wv.y * LOG2E;
                ws[(wj + 2) * 64 + wh] = wv.z * LOG2E;
                ws[(wj + 3) * 64 + wh] = wv.w * LOG2E;
            }
            __syncthreads();
#pragma unroll
            for (int jj = 0; jj < 8; ++jj) {
                float4 xq = *(float4*)&xs[jj * 64 + tb * 4];
                float4 wq = *(float4*)&ws[jj * 64 + th * 4];
                float xa[4] = {xq.x, xq.y, xq.z, xq.w};
                float wa[4] = {wq.x, wq.y, wq.z, wq.w};
#pragma unroll
                for (int bi = 0; bi < 4; ++bi)
#pragma unroll
                    for (int hh = 0; hh < 4; ++hh)
                        acc[bi][hh] = fmaf(xa[bi], wa[hh], acc[bi][hh]);
            }
        }
        float* dst = G + (size_t)r * BH_;
#pragma unroll
        for (int bi = 0; bi < 4; ++bi) {
            float4 o = make_float4(acc[bi][0], acc[bi][1], acc[bi][2], acc[bi][3]);
            *(float4*)(dst + (size_t)(b0 + tb * 4 + bi) * H_ + h0 + th * 4) = o;
        }
    }
}

// ---------- DPP reduce: full 64-lane sum into lane 63 ----------
template <int CTRL>
__device__ __forceinline__ float dpp_add(float p) {
    int s = __builtin_amdgcn_update_dpp(0, __float_as_int(p), CTRL, 0xf, 0xf, true);
    return p + __int_as_float(s);
}
__device__ __forceinline__ float reduce64(float p) {
    p = dpp_add<0x111>(p);   // row_shr:1
    p = dpp_add<0x112>(p);   // row_shr:2
    p = dpp_add<0x114>(p);   // row_shr:4
    p = dpp_add<0x118>(p);   // row_shr:8  -> lane15/31/47/63 hold 16-lane sums
    p = dpp_add<0x142>(p);   // row_bcast:15 -> lane31 = sum(0..31), lane63 = sum(32..63)
    p = dpp_add<0x143>(p);   // row_bcast:31 -> lane63 = sum(0..63)
    return p;
}

// 8 packed bf16 (uint4) -> 8 floats; high elements keep junk low-mantissa bits
__device__ __forceinline__ void cvt8(uint4 u, float4& a, float4& b) {
    a.x = __uint_as_float(u.x << 16);
    a.y = __uint_as_float(u.x);
    a.z = __uint_as_float(u.y << 16);
    a.w = __uint_as_float(u.y);
    b.x = __uint_as_float(u.z << 16);
    b.y = __uint_as_float(u.z);
    b.z = __uint_as_float(u.w << 16);
    b.w = __uint_as_float(u.w);
}

// 8-wide rational tree: accumulates (n, d) with d = prod q, n = sum v_k * prod_{j!=k} q_j.
// Clamp 15 keeps d <= 2^120 < f32 max. Also performs the A rank-1 update.
__device__ __forceinline__ void tree8(float (&Aq)[8], const uint4& uv, const uint4& uw,
                                      float xi, float& n, float& d) {
    float4 v0, v1, w0, w1;
    cvt8(uv, v0, v1);
    cvt8(uw, w0, w1);
    float va[8] = {v0.x, v0.y, v0.z, v0.w, v1.x, v1.y, v1.z, v1.w};
    float wa[8] = {w0.x, w0.y, w0.z, w0.w, w1.x, w1.y, w1.z, w1.w};
    float q[8];
#pragma unroll
    for (int k = 0; k < 8; ++k) {
        float e = __builtin_amdgcn_exp2f(fminf(15.f, -Aq[k]));
        q[k] = 1.f + e;
        Aq[k] = fmaf(wa[k], xi, Aq[k]);
    }
    float a01 = fmaf(va[0], q[1], va[1] * q[0]);
    float a23 = fmaf(va[2], q[3], va[3] * q[2]);
    float a45 = fmaf(va[4], q[5], va[5] * q[4]);
    float a67 = fmaf(va[6], q[7], va[7] * q[6]);
    float q01 = q[0] * q[1], q23 = q[2] * q[3];
    float q45 = q[4] * q[5], q67 = q[6] * q[7];
    float n0123 = fmaf(a01, q23, a23 * q01);
    float n4567 = fmaf(a45, q67, a67 * q45);
    float q0123 = q01 * q23, q4567 = q45 * q67;
    d = q0123 * q4567;
    n = fmaf(n0123, q4567, n4567 * q0123);
}

// ---------- main scan v2: 1 wave = 1 row, 16 h/lane, no LDS/barriers ----------
__global__ __launch_bounds__(256, 4) void nade_main(
    const float* __restrict__ px,            // [B, D]
    const float* __restrict__ c,             // [H]
    const unsigned short* __restrict__ VWb,  // bf16 images
    const float* __restrict__ G,             // [3][B][H] (log2 domain)
    const float* __restrict__ bias,          // [D]
    float* __restrict__ out)                 // [B, D]
{
    const int lane = threadIdx.x & 63;
    const int wid  = threadIdx.x >> 6;
    const int bid  = blockIdx.x;             // 0..1023
    const int s    = bid >> 8;               // 0..3
    const int rb   = bid & 255;              // row-block
    const int row  = rb * 4 + wid;           // this wave's row

    const int i0s = seg_bound(s), i1s = seg_bound(s + 1);

    // lane handles h = lane*8 .. +7 (half A) and 512 + lane*8 .. +7 (half B)
    const int hA = lane * 8;
    const int hB = 512 + hA;

    float AA[8], AB[8];
    {
        float4 c0 = *(const float4*)(c + hA);
        float4 c1 = *(const float4*)(c + hA + 4);
        float4 c2 = *(const float4*)(c + hB);
        float4 c3 = *(const float4*)(c + hB + 4);
        AA[0] = c0.x * LOG2E; AA[1] = c0.y * LOG2E; AA[2] = c0.z * LOG2E; AA[3] = c0.w * LOG2E;
        AA[4] = c1.x * LOG2E; AA[5] = c1.y * LOG2E; AA[6] = c1.z * LOG2E; AA[7] = c1.w * LOG2E;
        AB[0] = c2.x * LOG2E; AB[1] = c2.y * LOG2E; AB[2] = c2.z * LOG2E; AB[3] = c2.w * LOG2E;
        AB[4] = c3.x * LOG2E; AB[5] = c3.y * LOG2E; AB[6] = c3.z * LOG2E; AB[7] = c3.w * LOG2E;
        for (int r = 0; r < s; ++r) {
            const float* gp = G + (size_t)r * BH_ + (size_t)row * H_;
            float4 g0 = *(const float4*)(gp + hA);
            float4 g1 = *(const float4*)(gp + hA + 4);
            float4 g2 = *(const float4*)(gp + hB);
            float4 g3 = *(const float4*)(gp + hB + 4);
            AA[0] += g0.x; AA[1] += g0.y; AA[2] += g0.z; AA[3] += g0.w;
            AA[4] += g1.x; AA[5] += g1.y; AA[6] += g1.z; AA[7] += g1.w;
            AB[0] += g2.x; AB[1] += g2.y; AB[2] += g2.z; AB[3] += g2.w;
            AB[4] += g3.x; AB[5] += g3.y; AB[6] += g3.z; AB[7] += g3.w;
        }
    }

    const float* xp = px + (size_t)row * D_;
    // uint4 view of image i: 256 uint4 per image; lane's slices via immediate offsets:
    //   vA = +0, wA = +32, vB = +128, wB = +160 (uint4 units)
    const uint4* vw = (const uint4*)VWb + (size_t)i0s * 256 + (lane >> 5) * 64 + (lane & 31);

    uint4 vA = vw[0], wA = vw[32], vB = vw[128], wB = vw[160];
    vw += 256;
    float4 xq = *(const float4*)(xp + i0s);

    for (int ib = i0s; ib < i1s; ib += 4) {     // all segment lengths %4 == 0
        int xb = (ib + 4 < i1s) ? (ib + 4) : i0s;
        float4 xq_n = *(const float4*)(xp + xb);
        float xa[4] = {xq.x, xq.y, xq.z, xq.w};
        float pr[4];
#pragma unroll
        for (int j = 0; j < 4; ++j) {
            uint4 vAn = vw[0], wAn = vw[32], vBn = vw[128], wBn = vw[160];  // prefetch (padded past 784)
            vw += 256;
            float nA, dA, nB, dB;
            tree8(AA, vA, wA, xa[j], nA, dA);
            tree8(AB, vB, wB, xa[j], nB, dB);
            float p = fmaf(nA, __builtin_amdgcn_rcpf(dA),
                           nB * __builtin_amdgcn_rcpf(dB));
            pr[j] = reduce64(p);
            vA = vAn; wA = wAn; vB = vBn; wB = wBn;
        }
        float4 b4 = *(const float4*)(bias + ib);
        if (lane == 63) {
            float4 o = make_float4(pr[0] + b4.x, pr[1] + b4.y, pr[2] + b4.z, pr[3] + b4.w);
            *(float4*)(out + (size_t)row * D_ + ib) = o;
        }
        xq = xq_n;
    }
}

extern "C" void kernel_launch(void* const* d_in, const int* in_sizes, int n_in,
                              void* d_out, int out_size, void* d_ws, size_t ws_size,
                              hipStream_t stream) {
    const float* px   = (const float*)d_in[0];  // [B, D]
    const float* W    = (const float*)d_in[1];  // [H, D]
    const float* c    = (const float*)d_in[2];  // [H]
    const float* V    = (const float*)d_in[3];  // [D, H]
    const float* bias = (const float*)d_in[4];  // [D]
    float* out = (float*)d_out;                 // [B, D]

    unsigned short* VWb = (unsigned short*)d_ws;              // 788*4*512 ushorts = 3.23 MB
    float* G    = (float*)((char*)d_ws + (size_t)788 * 4096); // [3][B][H]

    // 800 pack blocks + 3 ranges x 256 G-matmul blocks
    prep<<<dim3(1568), 256, 0, stream>>>(V, W, px, VWb, G);

    // 1024 blocks x 4 waves; block = (segment, 4 consecutive rows), wave = 1 row
    nade_main<<<dim3(1024), 256, 0, stream>>>(px, c, VWb, G, bias, out);
}